// Round 1
// baseline (85.833 us; speedup 1.0000x reference)
//
#include <hip/hip_runtime.h>
#include <math.h>

#define NLEV 3
#define BATCH 16
#define NGT 32
#define NCLS 80
#define NA 3

// positions per level = B*A*H*W
#define P0 307200
#define P1 76800
#define P2 19200
#define PTOT (P0 + P1 + P2)

// ws layout (floats):
// [0..2]  softplus-sum of obj logits per level
// [3..5]  sum of obj_p at positives per level
// [6..8]  box squared-error sum per level
// [9..11] cls bce sum per level
// [12..14] npos per level

__device__ __forceinline__ float softplusf(float x) {
    // stable log(1+exp(x)) == max(x,0) + log1p(exp(-|x|))
    return fmaxf(x, 0.0f) + log1pf(expf(-fabsf(x)));
}

__global__ void zero_ws_kernel(float* __restrict__ ws) {
    if (threadIdx.x < 16) ws[threadIdx.x] = 0.0f;
}

__global__ void assign_kernel(const float* __restrict__ p0, const float* __restrict__ p1,
                              const float* __restrict__ p2,
                              const float* __restrict__ a0, const float* __restrict__ a1,
                              const float* __restrict__ a2,
                              const float* __restrict__ gtb, const int* __restrict__ gtl,
                              float* __restrict__ ws) {
    const int bid = blockIdx.x;
    const int lev = bid % NLEV;
    const int b   = bid / NLEV;

    const int Hs[NLEV]      = {80, 40, 20};
    const float strd[NLEV]  = {8.0f, 16.0f, 32.0f};
    const float* pred = (lev == 0) ? p0 : ((lev == 1) ? p1 : p2);
    const float* anc  = (lev == 0) ? a0 : ((lev == 1) ? a1 : a2);
    const int H = Hs[lev], W = Hs[lev];
    const int HW = H * W;
    const float stride = strd[lev];

    __shared__ int   s_key[NGT];
    __shared__ float s_iou[NGT];

    const int tid = threadIdx.x;

    float x1 = 0.f, y1 = 0.f, x2 = 0.f, y2 = 0.f, cx = 0.f, cy = 0.f;
    float biou = -1.0f;
    int ba = 0, gx = 0, gy = 0, key = -1;

    if (tid < NGT) {
        const float* g = gtb + (size_t)(b * NGT + tid) * 4;
        x1 = g[0]; y1 = g[1]; x2 = g[2]; y2 = g[3];
        cx = (x1 + x2) * 0.5f;
        cy = (y1 + y2) * 0.5f;
        gx = (int)(cx / stride); gx = gx < 0 ? 0 : (gx > W - 1 ? W - 1 : gx);
        gy = (int)(cy / stride); gy = gy < 0 ? 0 : (gy > H - 1 ? H - 1 : gy);
        const float area1 = (x2 - x1) * (y2 - y1);
        for (int aa = 0; aa < NA; ++aa) {
            const float* av = anc + ((size_t)aa * HW + (size_t)gy * W + gx) * 4;
            const float acx = av[0], acy = av[1], aw = av[2], ah = av[3];
            const float c1x = acx - aw * 0.5f, c1y = acy - ah * 0.5f;
            const float c2x = acx + aw * 0.5f, c2y = acy + ah * 0.5f;
            const float ltx = fmaxf(x1, c1x), lty = fmaxf(y1, c1y);
            const float rbx = fminf(x2, c2x), rby = fminf(y2, c2y);
            const float wx = fmaxf(rbx - ltx, 0.0f), wy = fmaxf(rby - lty, 0.0f);
            const float inter = wx * wy;
            const float iou = inter / (area1 + aw * ah - inter + 1e-16f);
            if (iou > biou) { biou = iou; ba = aa; }   // strict > keeps first max (jnp.argmax)
        }
        key = ba * HW + gy * W + gx;
        s_key[tid] = key;
        s_iou[tid] = biou;
    }
    __syncthreads();

    if (tid < NGT) {
        // chosen iff no other GT at same key has larger iou, nor equal iou with smaller index
        bool chosen = true;
        for (int m = 0; m < NGT; ++m) {
            if (m == tid) continue;
            if (s_key[m] == key) {
                const float im = s_iou[m];
                if (im > biou || (im == biou && m < tid)) chosen = false;
            }
        }
        if (chosen) {
            const float* av = anc + ((size_t)ba * HW + (size_t)gy * W + gx) * 4;
            const float acx = av[0], acy = av[1], aw = av[2], ah = av[3];
            const float gw = x2 - x1, gh = y2 - y1;
            const float tx = (cx - acx) * 0.125f;   // / STRIDES[0] = 8 (exact pow2)
            const float ty = (cy - acy) * 0.125f;
            const float tw = logf(gw / aw + 1e-16f);
            const float th = logf(gh / ah + 1e-16f);

            const float* f = pred + ((size_t)(b * NA + ba) * HW + (size_t)gy * W + gx) * (5 + NCLS);
            const float d0 = f[0] - tx, d1 = f[1] - ty, d2 = f[2] - tw, d3 = f[3] - th;
            const float boxsq = d0 * d0 + d1 * d1 + d2 * d2 + d3 * d3;
            const float objp = f[4];
            const int label = gtl[b * NGT + tid];
            float cs = 0.0f;
            for (int c = 0; c < NCLS; ++c) cs += softplusf(f[5 + c]);
            cs -= f[5 + label];

            atomicAdd(&ws[3 + lev], objp);
            atomicAdd(&ws[6 + lev], boxsq);
            atomicAdd(&ws[9 + lev], cs);
            atomicAdd(&ws[12 + lev], 1.0f);
        }
    }
}

// sum softplus(obj logit) over all positions of all 3 levels.
// P0 and P0+P1 are multiples of 256, so a 256-thread block never straddles levels.
__global__ void obj_kernel(const float* __restrict__ p0, const float* __restrict__ p1,
                           const float* __restrict__ p2, float* __restrict__ ws) {
    const int tid = threadIdx.x;
    const int i = blockIdx.x * blockDim.x + tid;

    int lev, pos;
    const float* p;
    if (i < P0)            { lev = 0; p = p0; pos = i; }
    else if (i < P0 + P1)  { lev = 1; p = p1; pos = i - P0; }
    else                   { lev = 2; p = p2; pos = i - P0 - P1; }

    float v = softplusf(p[(size_t)pos * (5 + NCLS) + 4]);

    // wave (64-lane) butterfly reduce
    for (int off = 32; off > 0; off >>= 1) v += __shfl_down(v, off);

    __shared__ float wsum[4];
    const int wid = tid >> 6, lane = tid & 63;
    if (lane == 0) wsum[wid] = v;
    __syncthreads();
    if (tid == 0) {
        const float s = wsum[0] + wsum[1] + wsum[2] + wsum[3];
        atomicAdd(&ws[lev], s);
    }
}

__global__ void finalize_kernel(const float* __restrict__ ws, float* __restrict__ out) {
    if (threadIdx.x == 0 && blockIdx.x == 0) {
        const float BKs[NLEV] = {(float)P0, (float)P1, (float)P2};
        float tb = 0.f, to = 0.f, tc = 0.f, tot = 0.f;
        for (int l = 0; l < NLEV; ++l) {
            const float sp = ws[l], po = ws[3 + l], bx = ws[6 + l], cl = ws[9 + l], np = ws[12 + l];
            const float denom = fmaxf(np, 1.0f);
            const float obj_l = (sp - po) / BKs[l];
            const float box_l = bx / denom;
            const float cls_l = cl / (denom * (float)NCLS);
            if (np > 0.f) { tb += box_l; tc += cls_l; }
            to += obj_l;
            tot += np;
        }
        if (tot > 0.f) { tb /= 3.0f; tc /= 3.0f; } else { tb = 0.f; tc = 0.f; }
        to /= 3.0f;
        out[0] = 0.05f * tb + 1.0f * to + 0.5f * tc;
    }
}

extern "C" void kernel_launch(void* const* d_in, const int* in_sizes, int n_in,
                              void* d_out, int out_size, void* d_ws, size_t ws_size,
                              hipStream_t stream) {
    // defensive pointer mapping by element count (all sizes distinct)
    const float* p[3] = {nullptr, nullptr, nullptr};
    const float* a[3] = {nullptr, nullptr, nullptr};
    const float* gtb = nullptr;
    const int*   gtl = nullptr;
    for (int i = 0; i < n_in; ++i) {
        switch (in_sizes[i]) {
            case 26112000: p[0] = (const float*)d_in[i]; break;
            case 6528000:  p[1] = (const float*)d_in[i]; break;
            case 1632000:  p[2] = (const float*)d_in[i]; break;
            case 76800:    a[0] = (const float*)d_in[i]; break;
            case 19200:    a[1] = (const float*)d_in[i]; break;
            case 4800:     a[2] = (const float*)d_in[i]; break;
            case 2048:     gtb  = (const float*)d_in[i]; break;
            case 512:      gtl  = (const int*)d_in[i];   break;
            default: break;
        }
    }
    // fallback to dict order if size-matching failed
    if (!p[0]) p[0] = (const float*)d_in[0];
    if (!a[0]) a[0] = (const float*)d_in[1];
    if (!p[1]) p[1] = (const float*)d_in[2];
    if (!a[1]) a[1] = (const float*)d_in[3];
    if (!p[2]) p[2] = (const float*)d_in[4];
    if (!a[2]) a[2] = (const float*)d_in[5];
    if (!gtb)  gtb  = (const float*)d_in[6];
    if (!gtl)  gtl  = (const int*)d_in[7];

    float* ws = (float*)d_ws;

    zero_ws_kernel<<<1, 64, 0, stream>>>(ws);
    assign_kernel<<<BATCH * NLEV, 64, 0, stream>>>(p[0], p[1], p[2], a[0], a[1], a[2], gtb, gtl, ws);
    obj_kernel<<<PTOT / 256, 256, 0, stream>>>(p[0], p[1], p[2], ws);
    finalize_kernel<<<1, 1, 0, stream>>>(ws, (float*)d_out);
}

// Round 2
// 69.893 us; speedup vs baseline: 1.2281x; 1.2281x over previous
//
#include <hip/hip_runtime.h>
#include <math.h>

#define NLEV 3
#define BATCH 16
#define NGT 32
#define NCLS 80
#define NA 3

// positions per level = B*A*H*W
#define P0 307200
#define P1 76800
#define P2 19200
#define PTOT (P0 + P1 + P2)

#define OBJ_BLOCKS (PTOT / 256)        // 1575; blocks never straddle levels
#define OBJ_B0 (P0 / 256)              // 1200
#define OBJ_B01 ((P0 + P1) / 256)      // 1500

// ws layout (floats):
// [0 .. OBJ_BLOCKS)          per-block obj softplus partial sums
// [4096 + bid*4 .. +4)       per-assign-block partials: {sum obj_p@pos, sum boxsq, sum cls, npos}
#define ASSIGN_OFF 4096

__device__ __forceinline__ float softplusf(float x) {
    // stable log(1+exp(x)) == max(x,0) + log1p(exp(-|x|))
    return fmaxf(x, 0.0f) + log1pf(expf(-fabsf(x)));
}

__global__ void assign_kernel(const float* __restrict__ p0, const float* __restrict__ p1,
                              const float* __restrict__ p2,
                              const float* __restrict__ a0, const float* __restrict__ a1,
                              const float* __restrict__ a2,
                              const float* __restrict__ gtb, const int* __restrict__ gtl,
                              float* __restrict__ ws) {
    const int bid = blockIdx.x;
    const int lev = bid % NLEV;
    const int b   = bid / NLEV;

    const int Hs[NLEV]      = {80, 40, 20};
    const float strd[NLEV]  = {8.0f, 16.0f, 32.0f};
    const float* pred = (lev == 0) ? p0 : ((lev == 1) ? p1 : p2);
    const float* anc  = (lev == 0) ? a0 : ((lev == 1) ? a1 : a2);
    const int H = Hs[lev], W = Hs[lev];
    const int HW = H * W;
    const float stride = strd[lev];

    __shared__ int   s_key[NGT];
    __shared__ float s_iou[NGT];

    const int tid = threadIdx.x;

    float x1 = 0.f, y1 = 0.f, x2 = 0.f, y2 = 0.f, cx = 0.f, cy = 0.f;
    float biou = -1.0f;
    int ba = 0, gx = 0, gy = 0, key = -1;

    if (tid < NGT) {
        const float* g = gtb + (size_t)(b * NGT + tid) * 4;
        x1 = g[0]; y1 = g[1]; x2 = g[2]; y2 = g[3];
        cx = (x1 + x2) * 0.5f;
        cy = (y1 + y2) * 0.5f;
        gx = (int)(cx / stride); gx = gx < 0 ? 0 : (gx > W - 1 ? W - 1 : gx);
        gy = (int)(cy / stride); gy = gy < 0 ? 0 : (gy > H - 1 ? H - 1 : gy);
        const float area1 = (x2 - x1) * (y2 - y1);
        for (int aa = 0; aa < NA; ++aa) {
            const float* av = anc + ((size_t)aa * HW + (size_t)gy * W + gx) * 4;
            const float acx = av[0], acy = av[1], aw = av[2], ah = av[3];
            const float c1x = acx - aw * 0.5f, c1y = acy - ah * 0.5f;
            const float c2x = acx + aw * 0.5f, c2y = acy + ah * 0.5f;
            const float ltx = fmaxf(x1, c1x), lty = fmaxf(y1, c1y);
            const float rbx = fminf(x2, c2x), rby = fminf(y2, c2y);
            const float wx = fmaxf(rbx - ltx, 0.0f), wy = fmaxf(rby - lty, 0.0f);
            const float inter = wx * wy;
            const float iou = inter / (area1 + aw * ah - inter + 1e-16f);
            if (iou > biou) { biou = iou; ba = aa; }   // strict > keeps first max (jnp.argmax)
        }
        key = ba * HW + gy * W + gx;
        s_key[tid] = key;
        s_iou[tid] = biou;
    }
    __syncthreads();

    // per-lane contributions (0 unless this GT is chosen)
    float c_obj = 0.f, c_box = 0.f, c_cls = 0.f, c_np = 0.f;

    if (tid < NGT) {
        // chosen iff no other GT at same key has larger iou, nor equal iou with smaller index
        bool chosen = true;
        for (int m = 0; m < NGT; ++m) {
            if (m == tid) continue;
            if (s_key[m] == key) {
                const float im = s_iou[m];
                if (im > biou || (im == biou && m < tid)) chosen = false;
            }
        }
        if (chosen) {
            const float* av = anc + ((size_t)ba * HW + (size_t)gy * W + gx) * 4;
            const float acx = av[0], acy = av[1], aw = av[2], ah = av[3];
            const float gw = x2 - x1, gh = y2 - y1;
            const float tx = (cx - acx) * 0.125f;   // / STRIDES[0] = 8 (exact pow2)
            const float ty = (cy - acy) * 0.125f;
            const float tw = logf(gw / aw + 1e-16f);
            const float th = logf(gh / ah + 1e-16f);

            const float* f = pred + ((size_t)(b * NA + ba) * HW + (size_t)gy * W + gx) * (5 + NCLS);
            const float d0 = f[0] - tx, d1 = f[1] - ty, d2 = f[2] - tw, d3 = f[3] - th;
            c_box = d0 * d0 + d1 * d1 + d2 * d2 + d3 * d3;
            c_obj = f[4];
            const int label = gtl[b * NGT + tid];
            float cs = 0.0f;
            for (int c = 0; c < NCLS; ++c) cs += softplusf(f[5 + c]);
            cs -= f[5 + label];
            c_cls = cs;
            c_np  = 1.0f;
        }
    }

    // single-wave block: butterfly reduce across all 64 lanes (inactive lanes hold 0)
    for (int off = 32; off > 0; off >>= 1) {
        c_obj += __shfl_down(c_obj, off);
        c_box += __shfl_down(c_box, off);
        c_cls += __shfl_down(c_cls, off);
        c_np  += __shfl_down(c_np,  off);
    }
    if (tid == 0) {
        float* dst = ws + ASSIGN_OFF + (size_t)bid * 4;
        dst[0] = c_obj; dst[1] = c_box; dst[2] = c_cls; dst[3] = c_np;
    }
}

// sum softplus(obj logit) over all positions; per-block partial (no atomics).
__global__ void obj_kernel(const float* __restrict__ p0, const float* __restrict__ p1,
                           const float* __restrict__ p2, float* __restrict__ ws) {
    const int tid = threadIdx.x;
    const int i = blockIdx.x * blockDim.x + tid;

    int pos;
    const float* p;
    if (i < P0)            { p = p0; pos = i; }
    else if (i < P0 + P1)  { p = p1; pos = i - P0; }
    else                   { p = p2; pos = i - P0 - P1; }

    float v = softplusf(p[(size_t)pos * (5 + NCLS) + 4]);

    for (int off = 32; off > 0; off >>= 1) v += __shfl_down(v, off);

    __shared__ float wsum[4];
    const int wid = tid >> 6, lane = tid & 63;
    if (lane == 0) wsum[wid] = v;
    __syncthreads();
    if (tid == 0) ws[blockIdx.x] = wsum[0] + wsum[1] + wsum[2] + wsum[3];
}

__global__ void finalize_kernel(const float* __restrict__ ws, float* __restrict__ out) {
    const int tid = threadIdx.x;
    const int lane = tid & 63, wid = tid >> 6;

    // reduce obj partials into per-level sums
    float a0 = 0.f, a1 = 0.f, a2 = 0.f;
    for (int i = tid; i < OBJ_BLOCKS; i += 256) {
        const float v = ws[i];
        if (i < OBJ_B0)       a0 += v;
        else if (i < OBJ_B01) a1 += v;
        else                  a2 += v;
    }
    for (int off = 32; off > 0; off >>= 1) {
        a0 += __shfl_down(a0, off);
        a1 += __shfl_down(a1, off);
        a2 += __shfl_down(a2, off);
    }
    __shared__ float red[4][3];
    if (lane == 0) { red[wid][0] = a0; red[wid][1] = a1; red[wid][2] = a2; }
    __syncthreads();

    if (tid == 0) {
        float sp[NLEV];
        for (int l = 0; l < NLEV; ++l)
            sp[l] = red[0][l] + red[1][l] + red[2][l] + red[3][l];

        // reduce assign partials (48 blocks x 4)
        float po[NLEV] = {0.f, 0.f, 0.f}, bx[NLEV] = {0.f, 0.f, 0.f};
        float cl[NLEV] = {0.f, 0.f, 0.f}, np[NLEV] = {0.f, 0.f, 0.f};
        for (int bid = 0; bid < BATCH * NLEV; ++bid) {
            const int l = bid % NLEV;
            const float* src = ws + ASSIGN_OFF + (size_t)bid * 4;
            po[l] += src[0]; bx[l] += src[1]; cl[l] += src[2]; np[l] += src[3];
        }

        const float BKs[NLEV] = {(float)P0, (float)P1, (float)P2};
        float tb = 0.f, to = 0.f, tc = 0.f, tot = 0.f;
        for (int l = 0; l < NLEV; ++l) {
            const float denom = fmaxf(np[l], 1.0f);
            const float obj_l = (sp[l] - po[l]) / BKs[l];
            const float box_l = bx[l] / denom;
            const float cls_l = cl[l] / (denom * (float)NCLS);
            if (np[l] > 0.f) { tb += box_l; tc += cls_l; }
            to += obj_l;
            tot += np[l];
        }
        if (tot > 0.f) { tb /= 3.0f; tc /= 3.0f; } else { tb = 0.f; tc = 0.f; }
        to /= 3.0f;
        out[0] = 0.05f * tb + 1.0f * to + 0.5f * tc;
    }
}

extern "C" void kernel_launch(void* const* d_in, const int* in_sizes, int n_in,
                              void* d_out, int out_size, void* d_ws, size_t ws_size,
                              hipStream_t stream) {
    // defensive pointer mapping by element count (all sizes distinct)
    const float* p[3] = {nullptr, nullptr, nullptr};
    const float* a[3] = {nullptr, nullptr, nullptr};
    const float* gtb = nullptr;
    const int*   gtl = nullptr;
    for (int i = 0; i < n_in; ++i) {
        switch (in_sizes[i]) {
            case 26112000: p[0] = (const float*)d_in[i]; break;
            case 6528000:  p[1] = (const float*)d_in[i]; break;
            case 1632000:  p[2] = (const float*)d_in[i]; break;
            case 76800:    a[0] = (const float*)d_in[i]; break;
            case 19200:    a[1] = (const float*)d_in[i]; break;
            case 4800:     a[2] = (const float*)d_in[i]; break;
            case 2048:     gtb  = (const float*)d_in[i]; break;
            case 512:      gtl  = (const int*)d_in[i];   break;
            default: break;
        }
    }
    if (!p[0]) p[0] = (const float*)d_in[0];
    if (!a[0]) a[0] = (const float*)d_in[1];
    if (!p[1]) p[1] = (const float*)d_in[2];
    if (!a[1]) a[1] = (const float*)d_in[3];
    if (!p[2]) p[2] = (const float*)d_in[4];
    if (!a[2]) a[2] = (const float*)d_in[5];
    if (!gtb)  gtb  = (const float*)d_in[6];
    if (!gtl)  gtl  = (const int*)d_in[7];

    float* ws = (float*)d_ws;

    assign_kernel<<<BATCH * NLEV, 64, 0, stream>>>(p[0], p[1], p[2], a[0], a[1], a[2], gtb, gtl, ws);
    obj_kernel<<<OBJ_BLOCKS, 256, 0, stream>>>(p[0], p[1], p[2], ws);
    finalize_kernel<<<1, 256, 0, stream>>>(ws, (float*)d_out);
}

// Round 3
// 30.587 us; speedup vs baseline: 2.8062x; 2.2851x over previous
//
#include <hip/hip_runtime.h>
#include <math.h>

#define NLEV 3
#define BATCH 16
#define NGT 32
#define NCLS 80
#define NA 3

// positions per level = B*A*H*W
#define P0 307200
#define P1 76800
#define P2 19200
#define PTOT (P0 + P1 + P2)

#define OBJ_BLOCKS (PTOT / 256)        // 1575; blocks never straddle levels
#define OBJ_B0 (P0 / 256)              // 1200
#define OBJ_B01 ((P0 + P1) / 256)      // 1500
#define NASSIGN (BATCH * NLEV)         // 48
#define NB (OBJ_BLOCKS + NASSIGN)

// ws layout (floats):
// [0 .. OBJ_BLOCKS)          per-block obj softplus partial sums
// [4096 + aid*4 .. +4)       per-(b,lev) partials: {sum obj_p@pos, sum boxsq, sum cls, npos}
#define ASSIGN_OFF 4096

__device__ __forceinline__ float softplusf(float x) {
    // stable log(1+exp(x)) == max(x,0) + log1p(exp(-|x|))
    return fmaxf(x, 0.0f) + log1pf(expf(-fabsf(x)));
}

__global__ void fused_kernel(const float* __restrict__ p0, const float* __restrict__ p1,
                             const float* __restrict__ p2,
                             const float* __restrict__ a0, const float* __restrict__ a1,
                             const float* __restrict__ a2,
                             const float* __restrict__ gtb, const int* __restrict__ gtl,
                             float* __restrict__ ws) {
    const int blk = blockIdx.x;
    const int tid = threadIdx.x;
    const int wid = tid >> 6, lane = tid & 63;

    __shared__ float wsum[4];
    __shared__ int      s_key[NGT];
    __shared__ float    s_iou[NGT];
    __shared__ unsigned s_off[NGT];      // element offset into pred, 0xFFFFFFFF = not chosen
    __shared__ float    s_t[NGT][4];
    __shared__ int      s_lab[NGT];
    __shared__ float    s_np;
    __shared__ float    s_red[4][3];

    if (blk < OBJ_BLOCKS) {
        // ---- obj duty: softplus over obj logits, per-block partial ----
        const int i = blk * 256 + tid;
        int pos;
        const float* p;
        if (i < P0)            { p = p0; pos = i; }
        else if (i < P0 + P1)  { p = p1; pos = i - P0; }
        else                   { p = p2; pos = i - P0 - P1; }

        float v = softplusf(p[(size_t)pos * (5 + NCLS) + 4]);
        for (int off = 32; off > 0; off >>= 1) v += __shfl_down(v, off);
        if (lane == 0) wsum[wid] = v;
        __syncthreads();
        if (tid == 0) ws[blk] = wsum[0] + wsum[1] + wsum[2] + wsum[3];
        return;
    }

    // ---- assign duty: one block per (b, lev) ----
    const int aid = blk - OBJ_BLOCKS;
    const int lev = aid % NLEV;
    const int b   = aid / NLEV;

    const int Hs[NLEV]     = {80, 40, 20};
    const float strd[NLEV] = {8.0f, 16.0f, 32.0f};
    const float* pred = (lev == 0) ? p0 : ((lev == 1) ? p1 : p2);
    const float* anc  = (lev == 0) ? a0 : ((lev == 1) ? a1 : a2);
    const int H = Hs[lev], W = Hs[lev];
    const int HW = H * W;
    const float stride = strd[lev];

    // stage 1a: per-GT best anchor (lanes 0..31 of wave 0)
    float x1 = 0.f, y1 = 0.f, x2 = 0.f, y2 = 0.f, cx = 0.f, cy = 0.f;
    float biou = -1.0f;
    int ba = 0, gx = 0, gy = 0, key = -1;

    if (tid < NGT) {
        const float* g = gtb + (size_t)(b * NGT + tid) * 4;
        x1 = g[0]; y1 = g[1]; x2 = g[2]; y2 = g[3];
        cx = (x1 + x2) * 0.5f;
        cy = (y1 + y2) * 0.5f;
        gx = (int)(cx / stride); gx = gx < 0 ? 0 : (gx > W - 1 ? W - 1 : gx);
        gy = (int)(cy / stride); gy = gy < 0 ? 0 : (gy > H - 1 ? H - 1 : gy);
        const float area1 = (x2 - x1) * (y2 - y1);
        for (int aa = 0; aa < NA; ++aa) {
            const float* av = anc + ((size_t)aa * HW + (size_t)gy * W + gx) * 4;
            const float acx = av[0], acy = av[1], aw = av[2], ah = av[3];
            const float c1x = acx - aw * 0.5f, c1y = acy - ah * 0.5f;
            const float c2x = acx + aw * 0.5f, c2y = acy + ah * 0.5f;
            const float ltx = fmaxf(x1, c1x), lty = fmaxf(y1, c1y);
            const float rbx = fminf(x2, c2x), rby = fminf(y2, c2y);
            const float wx = fmaxf(rbx - ltx, 0.0f), wy = fmaxf(rby - lty, 0.0f);
            const float inter = wx * wy;
            const float iou = inter / (area1 + aw * ah - inter + 1e-16f);
            if (iou > biou) { biou = iou; ba = aa; }   // strict > keeps first max (jnp.argmax)
        }
        key = ba * HW + gy * W + gx;
        s_key[tid] = key;
        s_iou[tid] = biou;
    }
    __syncthreads();

    // stage 1b: winner resolution + target precompute (lanes 0..31 of wave 0)
    if (tid < NGT) {
        bool chosen = true;
        for (int m = 0; m < NGT; ++m) {
            if (m == tid) continue;
            if (s_key[m] == key) {
                const float im = s_iou[m];
                if (im > biou || (im == biou && m < tid)) chosen = false;
            }
        }
        if (chosen) {
            const float* av = anc + ((size_t)ba * HW + (size_t)gy * W + gx) * 4;
            const float acx = av[0], acy = av[1], aw = av[2], ah = av[3];
            const float gw = x2 - x1, gh = y2 - y1;
            s_t[tid][0] = (cx - acx) * 0.125f;   // / STRIDES[0] = 8
            s_t[tid][1] = (cy - acy) * 0.125f;
            s_t[tid][2] = logf(gw / aw + 1e-16f);
            s_t[tid][3] = logf(gh / ah + 1e-16f);
            s_lab[tid]  = gtl[b * NGT + tid];
            s_off[tid]  = (unsigned)(((b * NA + ba) * HW + gy * W + gx) * (5 + NCLS));
        } else {
            s_off[tid] = 0xFFFFFFFFu;
        }
        const unsigned long long mm = __ballot(chosen);
        if (tid == 0) s_np = (float)__popcll(mm);
    }
    __syncthreads();

    // stage 2: all 4 waves; wave w handles GTs [w*8, w*8+8).
    // Lane i covers prediction element i (and i+64 when i<21): 2 parallel loads per GT.
    float accO = 0.f, accB = 0.f, accC = 0.f;
    for (int g = wid * 8; g < wid * 8 + 8; ++g) {
        const unsigned off = s_off[g];           // uniform per wave
        if (off == 0xFFFFFFFFu) continue;
        const float* f = pred + off;
        const int lab = s_lab[g];
        const float v0 = f[lane];
        if (lane < 4) {
            const float d = v0 - s_t[g][lane];
            accB += d * d;
        } else if (lane == 4) {
            accO += v0;
        } else {
            accC += softplusf(v0);
            if (lane - 5 == lab) accC -= v0;
        }
        if (lane < 21) {
            const float v1 = f[lane + 64];
            accC += softplusf(v1);
            if (lane + 59 == lab) accC -= v1;
        }
    }

    for (int off = 32; off > 0; off >>= 1) {
        accO += __shfl_down(accO, off);
        accB += __shfl_down(accB, off);
        accC += __shfl_down(accC, off);
    }
    if (lane == 0) { s_red[wid][0] = accO; s_red[wid][1] = accB; s_red[wid][2] = accC; }
    __syncthreads();
    if (tid == 0) {
        float* dst = ws + ASSIGN_OFF + (size_t)aid * 4;
        dst[0] = s_red[0][0] + s_red[1][0] + s_red[2][0] + s_red[3][0];
        dst[1] = s_red[0][1] + s_red[1][1] + s_red[2][1] + s_red[3][1];
        dst[2] = s_red[0][2] + s_red[1][2] + s_red[2][2] + s_red[3][2];
        dst[3] = s_np;
    }
}

__global__ void finalize_kernel(const float* __restrict__ ws, float* __restrict__ out) {
    const int tid = threadIdx.x;
    const int lane = tid & 63, wid = tid >> 6;

    // reduce obj partials into per-level sums (256 threads, strided)
    float a0 = 0.f, a1 = 0.f, a2 = 0.f;
    for (int i = tid; i < OBJ_BLOCKS; i += 256) {
        const float v = ws[i];
        if (i < OBJ_B0)       a0 += v;
        else if (i < OBJ_B01) a1 += v;
        else                  a2 += v;
    }
    for (int off = 32; off > 0; off >>= 1) {
        a0 += __shfl_down(a0, off);
        a1 += __shfl_down(a1, off);
        a2 += __shfl_down(a2, off);
    }
    __shared__ float red[4][3];
    if (lane == 0) { red[wid][0] = a0; red[wid][1] = a1; red[wid][2] = a2; }

    // reduce assign partials wave-parallel (wave 0: lane g < 48 owns record g)
    __shared__ float ared[4][NLEV];   // {po, bx, cl, np} x level
    if (wid == 0) {
        float po = 0.f, bx = 0.f, cl = 0.f, np = 0.f;
        int l = 0;
        if (lane < NASSIGN) {
            const float* src = ws + ASSIGN_OFF + (size_t)lane * 4;
            po = src[0]; bx = src[1]; cl = src[2]; np = src[3];
            l = lane % NLEV;
        }
        for (int lv = 0; lv < NLEV; ++lv) {
            float vpo = (l == lv && lane < NASSIGN) ? po : 0.f;
            float vbx = (l == lv && lane < NASSIGN) ? bx : 0.f;
            float vcl = (l == lv && lane < NASSIGN) ? cl : 0.f;
            float vnp = (l == lv && lane < NASSIGN) ? np : 0.f;
            for (int off = 32; off > 0; off >>= 1) {
                vpo += __shfl_down(vpo, off);
                vbx += __shfl_down(vbx, off);
                vcl += __shfl_down(vcl, off);
                vnp += __shfl_down(vnp, off);
            }
            if (lane == 0) { ared[0][lv] = vpo; ared[1][lv] = vbx; ared[2][lv] = vcl; ared[3][lv] = vnp; }
        }
    }
    __syncthreads();

    if (tid == 0) {
        const float BKs[NLEV] = {(float)P0, (float)P1, (float)P2};
        float tb = 0.f, to = 0.f, tc = 0.f, tot = 0.f;
        for (int l = 0; l < NLEV; ++l) {
            const float sp = red[0][l] + red[1][l] + red[2][l] + red[3][l];
            const float po = ared[0][l], bx = ared[1][l], cl = ared[2][l], np = ared[3][l];
            const float denom = fmaxf(np, 1.0f);
            const float obj_l = (sp - po) / BKs[l];
            const float box_l = bx / denom;
            const float cls_l = cl / (denom * (float)NCLS);
            if (np > 0.f) { tb += box_l; tc += cls_l; }
            to += obj_l;
            tot += np;
        }
        if (tot > 0.f) { tb /= 3.0f; tc /= 3.0f; } else { tb = 0.f; tc = 0.f; }
        to /= 3.0f;
        out[0] = 0.05f * tb + 1.0f * to + 0.5f * tc;
    }
}

extern "C" void kernel_launch(void* const* d_in, const int* in_sizes, int n_in,
                              void* d_out, int out_size, void* d_ws, size_t ws_size,
                              hipStream_t stream) {
    // defensive pointer mapping by element count (all sizes distinct)
    const float* p[3] = {nullptr, nullptr, nullptr};
    const float* a[3] = {nullptr, nullptr, nullptr};
    const float* gtb = nullptr;
    const int*   gtl = nullptr;
    for (int i = 0; i < n_in; ++i) {
        switch (in_sizes[i]) {
            case 26112000: p[0] = (const float*)d_in[i]; break;
            case 6528000:  p[1] = (const float*)d_in[i]; break;
            case 1632000:  p[2] = (const float*)d_in[i]; break;
            case 76800:    a[0] = (const float*)d_in[i]; break;
            case 19200:    a[1] = (const float*)d_in[i]; break;
            case 4800:     a[2] = (const float*)d_in[i]; break;
            case 2048:     gtb  = (const float*)d_in[i]; break;
            case 512:      gtl  = (const int*)d_in[i];   break;
            default: break;
        }
    }
    if (!p[0]) p[0] = (const float*)d_in[0];
    if (!a[0]) a[0] = (const float*)d_in[1];
    if (!p[1]) p[1] = (const float*)d_in[2];
    if (!a[1]) a[1] = (const float*)d_in[3];
    if (!p[2]) p[2] = (const float*)d_in[4];
    if (!a[2]) a[2] = (const float*)d_in[5];
    if (!gtb)  gtb  = (const float*)d_in[6];
    if (!gtl)  gtl  = (const int*)d_in[7];

    float* ws = (float*)d_ws;

    fused_kernel<<<NB, 256, 0, stream>>>(p[0], p[1], p[2], a[0], a[1], a[2], gtb, gtl, ws);
    finalize_kernel<<<1, 256, 0, stream>>>(ws, (float*)d_out);
}

// Round 4
// 25.913 us; speedup vs baseline: 3.3124x; 1.1804x over previous
//
#include <hip/hip_runtime.h>
#include <math.h>

#define NLEV 3
#define BATCH 16
#define NGT 32
#define NCLS 80
#define NA 3

// positions per level = B*A*H*W
#define P0 307200
#define P1 76800
#define P2 19200
#define PTOT (P0 + P1 + P2)

// obj: 1024 positions per block (256 threads x 4)
#define OBJ_NB0 300            // P0 / 1024
#define OBJ_NB1 75             // P1 / 1024
#define OBJ_NB2 19             // ceil(P2 / 1024)
#define OBJ_NB  (OBJ_NB0 + OBJ_NB1 + OBJ_NB2)   // 394
#define OBJ_B0  OBJ_NB0
#define OBJ_B01 (OBJ_NB0 + OBJ_NB1)             // 375

#define NASSIGN (BATCH * NLEV)  // 48
#define NB (NASSIGN + OBJ_NB)   // 442; assign blocks FIRST (longest dep chain)

// ws layout (floats):
// [0 .. OBJ_NB)            per-obj-block softplus partial sums
// [4096 + aid*4 .. +4)     per-(b,lev) partials: {sum obj_p@pos, sum boxsq, sum cls, npos}
#define ASSIGN_OFF 4096

__device__ __forceinline__ float softplusf(float x) {
    // stable log(1+exp(x)) == max(x,0) + log1p(exp(-|x|))
    return fmaxf(x, 0.0f) + log1pf(expf(-fabsf(x)));
}

__global__ void fused_kernel(const float* __restrict__ p0, const float* __restrict__ p1,
                             const float* __restrict__ p2,
                             const float* __restrict__ a0, const float* __restrict__ a1,
                             const float* __restrict__ a2,
                             const float* __restrict__ gtb, const int* __restrict__ gtl,
                             float* __restrict__ ws) {
    const int blk = blockIdx.x;
    const int tid = threadIdx.x;
    const int wid = tid >> 6, lane = tid & 63;

    __shared__ float wsum[4];
    __shared__ int      s_key[NGT];
    __shared__ float    s_iou[NGT];
    __shared__ unsigned s_off[NGT];      // element offset into pred, 0xFFFFFFFF = not chosen
    __shared__ float    s_t[NGT][4];
    __shared__ int      s_lab[NGT];
    __shared__ float    s_np;
    __shared__ float    s_red[4][3];

    if (blk >= NASSIGN) {
        // ---- obj duty: softplus over obj logits, 4 positions per thread ----
        const int ob = blk - NASSIGN;
        const float* p;
        int base, plim;
        if (ob < OBJ_NB0)      { p = p0; base = ob * 1024;               plim = P0; }
        else if (ob < OBJ_B01) { p = p1; base = (ob - OBJ_NB0) * 1024;   plim = P1; }
        else                   { p = p2; base = (ob - OBJ_B01) * 1024;   plim = P2; }

        float v = 0.0f;
        #pragma unroll
        for (int k = 0; k < 4; ++k) {
            const int pos = base + k * 256 + tid;
            if (pos < plim) v += softplusf(p[(size_t)pos * (5 + NCLS) + 4]);
        }
        for (int off = 32; off > 0; off >>= 1) v += __shfl_down(v, off);
        if (lane == 0) wsum[wid] = v;
        __syncthreads();
        if (tid == 0) ws[ob] = wsum[0] + wsum[1] + wsum[2] + wsum[3];
        return;
    }

    // ---- assign duty: one block per (b, lev) ----
    const int aid = blk;
    const int lev = aid % NLEV;
    const int b   = aid / NLEV;

    const int Hs[NLEV]     = {80, 40, 20};
    const float strd[NLEV] = {8.0f, 16.0f, 32.0f};
    const float* pred = (lev == 0) ? p0 : ((lev == 1) ? p1 : p2);
    const float* anc  = (lev == 0) ? a0 : ((lev == 1) ? a1 : a2);
    const int H = Hs[lev], W = Hs[lev];
    const int HW = H * W;
    const float stride = strd[lev];

    // stage 1a: per-GT best anchor (lanes 0..31 of wave 0)
    float x1 = 0.f, y1 = 0.f, x2 = 0.f, y2 = 0.f, cx = 0.f, cy = 0.f;
    float biou = -1.0f;
    int ba = 0, gx = 0, gy = 0, key = -1, lab = 0;

    if (tid < NGT) {
        const float* g = gtb + (size_t)(b * NGT + tid) * 4;
        lab = gtl[b * NGT + tid];          // independent load, issue early
        x1 = g[0]; y1 = g[1]; x2 = g[2]; y2 = g[3];
        cx = (x1 + x2) * 0.5f;
        cy = (y1 + y2) * 0.5f;
        gx = (int)(cx / stride); gx = gx < 0 ? 0 : (gx > W - 1 ? W - 1 : gx);
        gy = (int)(cy / stride); gy = gy < 0 ? 0 : (gy > H - 1 ? H - 1 : gy);
        const float area1 = (x2 - x1) * (y2 - y1);
        for (int aa = 0; aa < NA; ++aa) {
            const float* av = anc + ((size_t)aa * HW + (size_t)gy * W + gx) * 4;
            const float acx = av[0], acy = av[1], aw = av[2], ah = av[3];
            const float c1x = acx - aw * 0.5f, c1y = acy - ah * 0.5f;
            const float c2x = acx + aw * 0.5f, c2y = acy + ah * 0.5f;
            const float ltx = fmaxf(x1, c1x), lty = fmaxf(y1, c1y);
            const float rbx = fminf(x2, c2x), rby = fminf(y2, c2y);
            const float wx = fmaxf(rbx - ltx, 0.0f), wy = fmaxf(rby - lty, 0.0f);
            const float inter = wx * wy;
            const float iou = inter / (area1 + aw * ah - inter + 1e-16f);
            if (iou > biou) { biou = iou; ba = aa; }   // strict > keeps first max (jnp.argmax)
        }
        key = ba * HW + gy * W + gx;
        s_key[tid] = key;
        s_iou[tid] = biou;
    }
    __syncthreads();

    // stage 1b: winner resolution + target precompute (lanes 0..31 of wave 0)
    if (tid < NGT) {
        bool chosen = true;
        for (int m = 0; m < NGT; ++m) {
            if (m == tid) continue;
            if (s_key[m] == key) {
                const float im = s_iou[m];
                if (im > biou || (im == biou && m < tid)) chosen = false;
            }
        }
        if (chosen) {
            const float* av = anc + ((size_t)ba * HW + (size_t)gy * W + gx) * 4;
            const float acx = av[0], acy = av[1], aw = av[2], ah = av[3];
            const float gw = x2 - x1, gh = y2 - y1;
            s_t[tid][0] = (cx - acx) * 0.125f;   // / STRIDES[0] = 8
            s_t[tid][1] = (cy - acy) * 0.125f;
            s_t[tid][2] = logf(gw / aw + 1e-16f);
            s_t[tid][3] = logf(gh / ah + 1e-16f);
            s_lab[tid]  = lab;
            s_off[tid]  = (unsigned)(((b * NA + ba) * HW + gy * W + gx) * (5 + NCLS));
        } else {
            s_off[tid] = 0xFFFFFFFFu;
        }
        const unsigned long long mm = __ballot(chosen);
        if (tid == 0) s_np = (float)__popcll(mm);
    }
    __syncthreads();

    // stage 2: all 4 waves; wave w handles GTs [w*8, w*8+8).
    // Lane i covers prediction element i (and i+64 when i<21): 2 parallel loads per GT.
    float accO = 0.f, accB = 0.f, accC = 0.f;
    for (int g = wid * 8; g < wid * 8 + 8; ++g) {
        const unsigned off = s_off[g];           // uniform per wave
        if (off == 0xFFFFFFFFu) continue;
        const float* f = pred + off;
        const int glab = s_lab[g];
        const float v0 = f[lane];
        if (lane < 4) {
            const float d = v0 - s_t[g][lane];
            accB += d * d;
        } else if (lane == 4) {
            accO += v0;
        } else {
            accC += softplusf(v0);
            if (lane - 5 == glab) accC -= v0;
        }
        if (lane < 21) {
            const float v1 = f[lane + 64];
            accC += softplusf(v1);
            if (lane + 59 == glab) accC -= v1;
        }
    }

    for (int off = 32; off > 0; off >>= 1) {
        accO += __shfl_down(accO, off);
        accB += __shfl_down(accB, off);
        accC += __shfl_down(accC, off);
    }
    if (lane == 0) { s_red[wid][0] = accO; s_red[wid][1] = accB; s_red[wid][2] = accC; }
    __syncthreads();
    if (tid == 0) {
        float* dst = ws + ASSIGN_OFF + (size_t)aid * 4;
        dst[0] = s_red[0][0] + s_red[1][0] + s_red[2][0] + s_red[3][0];
        dst[1] = s_red[0][1] + s_red[1][1] + s_red[2][1] + s_red[3][1];
        dst[2] = s_red[0][2] + s_red[1][2] + s_red[2][2] + s_red[3][2];
        dst[3] = s_np;
    }
}

__global__ void finalize_kernel(const float* __restrict__ ws, float* __restrict__ out) {
    const int tid = threadIdx.x;
    const int lane = tid & 63, wid = tid >> 6;

    // reduce obj partials into per-level sums (256 threads, strided; 394 entries)
    float a0 = 0.f, a1 = 0.f, a2 = 0.f;
    for (int i = tid; i < OBJ_NB; i += 256) {
        const float v = ws[i];
        if (i < OBJ_B0)       a0 += v;
        else if (i < OBJ_B01) a1 += v;
        else                  a2 += v;
    }
    for (int off = 32; off > 0; off >>= 1) {
        a0 += __shfl_down(a0, off);
        a1 += __shfl_down(a1, off);
        a2 += __shfl_down(a2, off);
    }
    __shared__ float red[4][3];
    if (lane == 0) { red[wid][0] = a0; red[wid][1] = a1; red[wid][2] = a2; }

    // reduce assign partials wave-parallel (wave 1: lane g < 48 owns record g)
    __shared__ float ared[4][NLEV];   // {po, bx, cl, np} x level
    if (wid == 1) {
        float po = 0.f, bx = 0.f, cl = 0.f, np = 0.f;
        int l = 0;
        if (lane < NASSIGN) {
            const float* src = ws + ASSIGN_OFF + (size_t)lane * 4;
            po = src[0]; bx = src[1]; cl = src[2]; np = src[3];
            l = lane % NLEV;
        }
        for (int lv = 0; lv < NLEV; ++lv) {
            float vpo = (l == lv && lane < NASSIGN) ? po : 0.f;
            float vbx = (l == lv && lane < NASSIGN) ? bx : 0.f;
            float vcl = (l == lv && lane < NASSIGN) ? cl : 0.f;
            float vnp = (l == lv && lane < NASSIGN) ? np : 0.f;
            for (int off = 32; off > 0; off >>= 1) {
                vpo += __shfl_down(vpo, off);
                vbx += __shfl_down(vbx, off);
                vcl += __shfl_down(vcl, off);
                vnp += __shfl_down(vnp, off);
            }
            if (lane == 0) { ared[0][lv] = vpo; ared[1][lv] = vbx; ared[2][lv] = vcl; ared[3][lv] = vnp; }
        }
    }
    __syncthreads();

    if (tid == 0) {
        const float BKs[NLEV] = {(float)P0, (float)P1, (float)P2};
        float tb = 0.f, to = 0.f, tc = 0.f, tot = 0.f;
        for (int l = 0; l < NLEV; ++l) {
            const float sp = red[0][l] + red[1][l] + red[2][l] + red[3][l];
            const float po = ared[0][l], bx = ared[1][l], cl = ared[2][l], np = ared[3][l];
            const float denom = fmaxf(np, 1.0f);
            const float obj_l = (sp - po) / BKs[l];
            const float box_l = bx / denom;
            const float cls_l = cl / (denom * (float)NCLS);
            if (np > 0.f) { tb += box_l; tc += cls_l; }
            to += obj_l;
            tot += np;
        }
        if (tot > 0.f) { tb /= 3.0f; tc /= 3.0f; } else { tb = 0.f; tc = 0.f; }
        to /= 3.0f;
        out[0] = 0.05f * tb + 1.0f * to + 0.5f * tc;
    }
}

extern "C" void kernel_launch(void* const* d_in, const int* in_sizes, int n_in,
                              void* d_out, int out_size, void* d_ws, size_t ws_size,
                              hipStream_t stream) {
    // defensive pointer mapping by element count (all sizes distinct)
    const float* p[3] = {nullptr, nullptr, nullptr};
    const float* a[3] = {nullptr, nullptr, nullptr};
    const float* gtb = nullptr;
    const int*   gtl = nullptr;
    for (int i = 0; i < n_in; ++i) {
        switch (in_sizes[i]) {
            case 26112000: p[0] = (const float*)d_in[i]; break;
            case 6528000:  p[1] = (const float*)d_in[i]; break;
            case 1632000:  p[2] = (const float*)d_in[i]; break;
            case 76800:    a[0] = (const float*)d_in[i]; break;
            case 19200:    a[1] = (const float*)d_in[i]; break;
            case 4800:     a[2] = (const float*)d_in[i]; break;
            case 2048:     gtb  = (const float*)d_in[i]; break;
            case 512:      gtl  = (const int*)d_in[i];   break;
            default: break;
        }
    }
    if (!p[0]) p[0] = (const float*)d_in[0];
    if (!a[0]) a[0] = (const float*)d_in[1];
    if (!p[1]) p[1] = (const float*)d_in[2];
    if (!a[1]) a[1] = (const float*)d_in[3];
    if (!p[2]) p[2] = (const float*)d_in[4];
    if (!a[2]) a[2] = (const float*)d_in[5];
    if (!gtb)  gtb  = (const float*)d_in[6];
    if (!gtl)  gtl  = (const int*)d_in[7];

    float* ws = (float*)d_ws;

    fused_kernel<<<NB, 256, 0, stream>>>(p[0], p[1], p[2], a[0], a[1], a[2], gtb, gtl, ws);
    finalize_kernel<<<1, 256, 0, stream>>>(ws, (float*)d_out);
}